// Round 15
// baseline (549.567 us; speedup 1.0000x reference)
//
#include <hip/hip_runtime.h>

#define B_ 8192
#define D_ 1024
#define O_ 1024
#define G_ 512
#define H_ 2048
#define E_ 8
#define ROWSP (B_ * 2 + E_ * 128)   // padded routed rows = 17408
#define TAU 0.01f

typedef unsigned short u16;
using f32x4  = __attribute__((ext_vector_type(4))) float;
using s16x8  = __attribute__((ext_vector_type(8))) short;

__device__ __forceinline__ u16 f2bf(float f) {
  union { float f; unsigned u; } v; v.f = f;
  unsigned r = v.u + 0x7FFFu + ((v.u >> 16) & 1u);
  return (u16)(r >> 16);
}
__device__ __forceinline__ float bf2f(u16 h) {
  union { unsigned u; float f; } v; v.u = ((unsigned)h) << 16; return v.f;
}
__device__ __forceinline__ void gload16(const void* g, void* l) {
  __builtin_amdgcn_global_load_lds(
      (const __attribute__((address_space(1))) unsigned int*)g,
      (__attribute__((address_space(3))) unsigned int*)l, 16, 0, 0);
}
// XCD-aware swizzle: hardware bid -> work id; XCD(bid)=bid%8 gets contiguous works.
__device__ __forceinline__ int xcd_swz(int bid, int nwg) {
  return (bid & 7) * (nwg >> 3) + (bid >> 3);
}
// Swizzled staging (proven R5): thread li stages logical chunk (li&3)^((li>>3)&3) of
// row li>>2 into physical slot li&3 (linear dest li*16B). Global 64B row contiguous.
__device__ __forceinline__ int stage_kc(int t) {
  return (((t & 3) ^ ((t >> 3) & 3)) * 8);
}
// 16x16x32 fragment read within a 64x32 swizzled subtile (2048 u16), proven R5
// (0 conflicts measured): row = i*16 + (lane&15), chunk = (lane>>4) ^ ((lane>>1)&3).
// frag_idx(lane,i) = frag_idx(lane,0) + i*512 (u16) — fragment stride is constant.
__device__ __forceinline__ int frag_idx(int lane, int i) {
  int row = i * 16 + (lane & 15);
  int s = (lane >> 4) ^ ((lane >> 1) & 3);
  return (row * 4 + s) * 8;
}

// ---------- merged preprocessing: cast x (hi/lo) + transpose-cast Wg1/W1/W2 + zero ctrs ----------
#define PREP_CAST_BLK (B_ * D_ / 4 / 256)          // 8192
#define PREP_WG1_BLK  ((G_ / 32) * (D_ / 32))      // 512
#define PREP_W1_BLK   ((H_ / 32) * (D_ / 32) * E_) // 16384
#define PREP_W2_BLK   ((O_ / 32) * (H_ / 32) * E_) // 16384

// Vectorized transpose-cast: float4 reads, ushort4 writes (both coalesced).
__device__ __forceinline__ void tr_cast_tile(const float* __restrict__ src,
                                             u16* __restrict__ dhi,
                                             u16* __restrict__ dlo,
                                             int R, int C, int bx, int by,
                                             float (*tile)[33], int t) {
  int c0 = bx * 32, r0 = by * 32;
  {
    int row = t >> 3, col4 = (t & 7) * 4;
    float4 v = *(const float4*)(src + (size_t)(r0 + row) * C + c0 + col4);
    tile[row][col4] = v.x; tile[row][col4 + 1] = v.y;
    tile[row][col4 + 2] = v.z; tile[row][col4 + 3] = v.w;
  }
  __syncthreads();
  {
    int c = t >> 3, r4 = (t & 7) * 4;
    float v0 = tile[r4 + 0][c], v1 = tile[r4 + 1][c];
    float v2 = tile[r4 + 2][c], v3 = tile[r4 + 3][c];
    ushort4 hi;
    hi.x = f2bf(v0); hi.y = f2bf(v1); hi.z = f2bf(v2); hi.w = f2bf(v3);
    *(ushort4*)(dhi + (size_t)(c0 + c) * R + r0 + r4) = hi;
    if (dlo) {
      ushort4 lo;
      lo.x = f2bf(v0 - bf2f(hi.x)); lo.y = f2bf(v1 - bf2f(hi.y));
      lo.z = f2bf(v2 - bf2f(hi.z)); lo.w = f2bf(v3 - bf2f(hi.w));
      *(ushort4*)(dlo + (size_t)(c0 + c) * R + r0 + r4) = lo;
    }
  }
}

__global__ __launch_bounds__(256) void k_prep(const float* __restrict__ x,
                                              u16* __restrict__ xhi, u16* __restrict__ xlo,
                                              const float* __restrict__ Wg1,
                                              u16* __restrict__ wg1h, u16* __restrict__ wg1l,
                                              const float* __restrict__ W1, u16* __restrict__ w1t,
                                              const float* __restrict__ W2, u16* __restrict__ w2t,
                                              int* __restrict__ zeroarea) {
  __shared__ float tile[32][33];
  int t = threadIdx.x;
  int b = blockIdx.x;
  if (b < PREP_CAST_BLK) {
    if (b == 0 && t < 32) zeroarea[t] = 0;   // counts/fill/ent/nflag
    int i = b * 256 + t;
    float4 v = ((const float4*)x)[i];
    u16 h0 = f2bf(v.x), h1 = f2bf(v.y), h2 = f2bf(v.z), h3 = f2bf(v.w);
    ushort4 hi; hi.x = h0; hi.y = h1; hi.z = h2; hi.w = h3;
    ushort4 lo;
    lo.x = f2bf(v.x - bf2f(h0)); lo.y = f2bf(v.y - bf2f(h1));
    lo.z = f2bf(v.z - bf2f(h2)); lo.w = f2bf(v.w - bf2f(h3));
    ((ushort4*)xhi)[i] = hi; ((ushort4*)xlo)[i] = lo;
    return;
  }
  b -= PREP_CAST_BLK;
  if (b < PREP_WG1_BLK) {
    tr_cast_tile(Wg1, wg1h, wg1l, D_, G_, b & 15, b >> 4, tile, t);
    return;
  }
  b -= PREP_WG1_BLK;
  if (b < PREP_W1_BLK) {
    int e = b >> 11, rr = b & 2047;
    size_t ofs = (size_t)e * D_ * H_;
    tr_cast_tile(W1 + ofs, w1t + ofs, nullptr, D_, H_, rr & 63, rr >> 6, tile, t);
    return;
  }
  b -= PREP_W1_BLK;
  {
    int e = b >> 11, rr = b & 2047;
    size_t ofs = (size_t)e * H_ * O_;
    tr_cast_tile(W2 + ofs, w2t + ofs, nullptr, H_, O_, rr & 31, rr >> 5, tile, t);
  }
}

// ---------- gate GEMM1: G1 = relu(x @ Wg1 + bg1), 3-pass split bf16, f32 out ----------
// 64x128 tiles (512 blocks). 4 waves 2M x 2N; wave = 32x64, acc[2][4].
__global__ __launch_bounds__(256) void k_gate_gemm1(const u16* __restrict__ xhi,
                                                    const u16* __restrict__ xlo,
                                                    const u16* __restrict__ whi,
                                                    const u16* __restrict__ wlo,
                                                    const float* __restrict__ bg1,
                                                    float* __restrict__ G1) {
  __shared__ u16 Ah[2048], Al[2048], Bh[4096], Bl[4096];
  int work = xcd_swz(blockIdx.x, (G_ / 128) * (B_ / 64));
  int m0 = (work >> 2) * 64, n0 = (work & 3) * 128;
  int t = threadIdx.x;
  int wave = t >> 6, lane = t & 63;
  int wm = wave >> 1, wn = wave & 1;

  const f32x4 z = {0.f, 0.f, 0.f, 0.f};
  f32x4 acc[2][4];
#pragma unroll
  for (int i = 0; i < 2; ++i)
#pragma unroll
    for (int j = 0; j < 4; ++j) acc[i][j] = z;

  int ar = t >> 2, ac = stage_kc(t);
  const u16* xh0 = xhi + (size_t)(m0 + ar) * D_ + ac;
  const u16* xl0 = xlo + (size_t)(m0 + ar) * D_ + ac;
  const u16* wh0 = whi + (size_t)(n0 + ar) * D_ + ac;
  const u16* wh1 = whi + (size_t)(n0 + 64 + ar) * D_ + ac;
  const u16* wl0 = wlo + (size_t)(n0 + ar) * D_ + ac;
  const u16* wl1 = wlo + (size_t)(n0 + 64 + ar) * D_ + ac;

  for (int k0 = 0; k0 < D_; k0 += 32) {
    gload16(xh0 + k0, &Ah[t * 8]);
    gload16(xl0 + k0, &Al[t * 8]);
    gload16(wh0 + k0, &Bh[t * 8]); gload16(wh1 + k0, &Bh[2048 + t * 8]);
    gload16(wl0 + k0, &Bl[t * 8]); gload16(wl1 + k0, &Bl[2048 + t * 8]);
    __syncthreads();
    s16x8 ah[2], al[2], bh[4], bl[4];
#pragma unroll
    for (int i = 0; i < 2; ++i) {
      ah[i] = *(const s16x8*)&Ah[frag_idx(lane, wm * 2 + i)];
      al[i] = *(const s16x8*)&Al[frag_idx(lane, wm * 2 + i)];
    }
#pragma unroll
    for (int j = 0; j < 4; ++j) {
      bh[j] = *(const s16x8*)&Bh[wn * 2048 + frag_idx(lane, j)];
      bl[j] = *(const s16x8*)&Bl[wn * 2048 + frag_idx(lane, j)];
    }
#pragma unroll
    for (int i = 0; i < 2; ++i)
#pragma unroll
      for (int j = 0; j < 4; ++j) {
        acc[i][j] = __builtin_amdgcn_mfma_f32_16x16x32_bf16(ah[i], bh[j], acc[i][j], 0, 0, 0);
        acc[i][j] = __builtin_amdgcn_mfma_f32_16x16x32_bf16(ah[i], bl[j], acc[i][j], 0, 0, 0);
        acc[i][j] = __builtin_amdgcn_mfma_f32_16x16x32_bf16(al[i], bh[j], acc[i][j], 0, 0, 0);
      }
    __syncthreads();
  }
#pragma unroll
  for (int j = 0; j < 4; ++j) {
    int col = n0 + wn * 64 + j * 16 + (lane & 15);
    float bias = bg1[col];
#pragma unroll
    for (int i = 0; i < 2; ++i)
#pragma unroll
      for (int q = 0; q < 4; ++q) {
        int row = m0 + wm * 32 + i * 16 + (lane >> 4) * 4 + q;
        float v = acc[i][j][q] + bias;
        G1[(size_t)row * G_ + col] = v > 0.f ? v : 0.f;
      }
  }
}

// ---------- gate logits: L = G1 @ Wg2 + bg2 (fp32, wave per row) + near-tie flagging ----------
__global__ __launch_bounds__(256) void k_gate_logits(const float* __restrict__ G1,
                                                     const float* __restrict__ Wg2,
                                                     const float* __restrict__ bg2,
                                                     float* __restrict__ logits,
                                                     int* __restrict__ flaglist,
                                                     int* __restrict__ nflag) {
  int t = threadIdx.x, wave = t >> 6, lane = t & 63;
  int row = blockIdx.x * 4 + wave;

  float4 g0 = *(const float4*)(G1 + (size_t)row * G_ + lane * 8);
  float4 g1 = *(const float4*)(G1 + (size_t)row * G_ + lane * 8 + 4);
  float g[8] = {g0.x, g0.y, g0.z, g0.w, g1.x, g1.y, g1.z, g1.w};
  float p[8] = {0, 0, 0, 0, 0, 0, 0, 0};
#pragma unroll
  for (int cc = 0; cc < 8; ++cc) {
    int c = lane * 8 + cc;
    float4 w0 = *(const float4*)(Wg2 + c * 8);
    float4 w1 = *(const float4*)(Wg2 + c * 8 + 4);
    p[0] += g[cc] * w0.x; p[1] += g[cc] * w0.y; p[2] += g[cc] * w0.z; p[3] += g[cc] * w0.w;
    p[4] += g[cc] * w1.x; p[5] += g[cc] * w1.y; p[6] += g[cc] * w1.z; p[7] += g[cc] * w1.w;
  }
#pragma unroll
  for (int off = 32; off >= 1; off >>= 1)
#pragma unroll
    for (int e = 0; e < 8; ++e) p[e] += __shfl_xor(p[e], off);
  if (lane == 0) {
    float l1 = -1e30f, l2 = -1e30f, l3 = -1e30f;
#pragma unroll
    for (int e = 0; e < 8; ++e) {
      float v = p[e] + bg2[e];
      logits[(size_t)row * 8 + e] = v;
      if (v > l1) { l3 = l2; l2 = l1; l1 = v; }
      else if (v > l2) { l3 = l2; l2 = v; }
      else if (v > l3) { l3 = v; }
    }
    if (l2 - l3 < TAU) {
      int pos = atomicAdd(nflag, 1);
      flaglist[pos] = row;
    }
  }
}

// ---------- exact fp32 recompute for flagged rows ----------
__global__ __launch_bounds__(256) void k_gate_fixup(const float* __restrict__ x,
                                                    const float* __restrict__ Wg1,
                                                    const float* __restrict__ bg1,
                                                    const float* __restrict__ Wg2,
                                                    const float* __restrict__ bg2,
                                                    const int* __restrict__ flaglist,
                                                    const int* __restrict__ nflag,
                                                    float* __restrict__ logits) {
  __shared__ float xs[1024];
  __shared__ float red[256][9];
  int t = threadIdx.x;
  int n = *nflag;
  for (int i = blockIdx.x; i < n; i += gridDim.x) {
    int row = flaglist[i];
    ((float4*)xs)[t] = ((const float4*)(x + (size_t)row * D_))[t];
    __syncthreads();
    int c0 = t * 2;
    float h0 = 0.f, h1 = 0.f;
#pragma unroll 8
    for (int d = 0; d < D_; ++d) {
      float xv = xs[d];
      float2 w = *(const float2*)(Wg1 + (size_t)d * G_ + c0);
      h0 += xv * w.x; h1 += xv * w.y;
    }
    h0 += bg1[c0]; h1 += bg1[c0 + 1];
    h0 = h0 > 0.f ? h0 : 0.f; h1 = h1 > 0.f ? h1 : 0.f;
#pragma unroll
    for (int e = 0; e < 8; ++e)
      red[t][e] = h0 * Wg2[c0 * 8 + e] + h1 * Wg2[(c0 + 1) * 8 + e];
    __syncthreads();
    for (int s = 128; s >= 1; s >>= 1) {
      if (t < s) {
#pragma unroll
        for (int e = 0; e < 8; ++e) red[t][e] += red[t + s][e];
      }
      __syncthreads();
    }
    if (t < 8) logits[(size_t)row * 8 + t] = red[0][t] + bg2[t];
    __syncthreads();
  }
}

// ---------- final gate ----------
__global__ __launch_bounds__(256) void k_gate_final(const float* __restrict__ logits,
                                                    int* __restrict__ topidx,
                                                    float* __restrict__ wnorm,
                                                    int* __restrict__ counts,
                                                    float* __restrict__ entacc) {
  __shared__ int cnt_s[8];
  __shared__ float ent_s[4];
  int t = threadIdx.x;
  if (t < 8) cnt_s[t] = 0;
  __syncthreads();
  int row = blockIdx.x * 256 + t;
  float4 a = ((const float4*)logits)[(size_t)row * 2];
  float4 b = ((const float4*)logits)[(size_t)row * 2 + 1];
  float L[8] = {a.x, a.y, a.z, a.w, b.x, b.y, b.z, b.w};
  float m = L[0];
#pragma unroll
  for (int e = 1; e < 8; ++e) m = fmaxf(m, L[e]);
  float s[8], Z = 0.f;
#pragma unroll
  for (int e = 0; e < 8; ++e) { s[e] = expf(L[e] - m); Z += s[e]; }
  float inv = 1.f / Z;
  float sc[8];
#pragma unroll
  for (int e = 0; e < 8; ++e) sc[e] = s[e] * inv;
  int i1 = 0;
#pragma unroll
  for (int e = 1; e < 8; ++e) if (L[e] > L[i1]) i1 = e;
  int i2 = (i1 == 0) ? 1 : 0;
#pragma unroll
  for (int e = 0; e < 8; ++e) if (e != i1 && L[e] > L[i2]) i2 = e;
  float s1 = sc[i1], s2 = sc[i2];
  float denom = s1 + s2 + 1e-9f;
  topidx[row * 2] = i1; topidx[row * 2 + 1] = i2;
  wnorm[row * 2] = s1 / denom; wnorm[row * 2 + 1] = s2 / denom;
  atomicAdd(&cnt_s[i1], 1); atomicAdd(&cnt_s[i2], 1);
  float ent = 0.f;
#pragma unroll
  for (int e = 0; e < 8; ++e) ent -= sc[e] * logf(sc[e] + 1e-9f);
#pragma unroll
  for (int off = 32; off >= 1; off >>= 1) ent += __shfl_xor(ent, off);
  if ((t & 63) == 0) ent_s[t >> 6] = ent;
  __syncthreads();
  if (t == 0) atomicAdd(entacc, ent_s[0] + ent_s[1] + ent_s[2] + ent_s[3]);
  if (t < 8) atomicAdd(&counts[t], cnt_s[t]);
}

// ---------- scatter routing (+ inline scan: every block derives aoff; block 0 writes aux) ----------
__global__ __launch_bounds__(256) void k_scatter(const int* __restrict__ topidx,
                                                 const float* __restrict__ wnorm,
                                                 const int* __restrict__ counts,
                                                 const float* __restrict__ entacc,
                                                 int* __restrict__ fill,
                                                 int* __restrict__ tok_list,
                                                 float* __restrict__ wroute,
                                                 int* __restrict__ pos_of,
                                                 int* __restrict__ aoff,
                                                 float* __restrict__ aux_out) {
  __shared__ int aoff_s[9];
  int t = threadIdx.x;
  if (t == 0) {
    int off = 0; aoff_s[0] = 0;
    for (int e = 0; e < 8; ++e) {
      off += ((counts[e] + 127) >> 7) << 7;
      aoff_s[e + 1] = off;
    }
    if (blockIdx.x == 0) {
      for (int e = 0; e < 9; ++e) aoff[e] = aoff_s[e];
      float mean = 0.f, ld[8];
      for (int e = 0; e < 8; ++e) { ld[e] = (float)counts[e] / (8192.0f + 1e-9f); mean += ld[e]; }
      mean *= 0.125f;
      float var = 0.f;
      for (int e = 0; e < 8; ++e) { float d = ld[e] - mean; var += d * d; }
      var *= (1.0f / 7.0f);
      *aux_out = var + entacc[0] / 8192.0f;
    }
  }
  __syncthreads();
  int i = blockIdx.x * 256 + t;
  int e = topidx[i];
  int pos = aoff_s[e] + atomicAdd(&fill[e], 1);
  tok_list[pos] = i >> 1;
  wroute[pos] = wnorm[i];
  pos_of[i] = pos;
}

// ==================== R5-proven 128x128 expert GEMMs, unroll-2 invariant addressing ====================
// 4 waves (2M x 2N), per-wave 64x64 (acc[4][4]). BK=32, dbuf, one barrier per K-step.
// All LDS read/write addresses are loop-invariant; buffer parity is compile-time via
// 2x unroll (fragment offsets fold into ds_read imm; +32-chunk folds into load imm).

// ---------- expert GEMM1: h = relu(gather(x) @ W1[e] + b1[e]) -> bf16 ----------
__global__ __launch_bounds__(256) void k_egemm1(const u16* __restrict__ xhi,
                                                const u16* __restrict__ w1t,
                                                const float* __restrict__ b1v,
                                                const int* __restrict__ tok_list,
                                                const int* __restrict__ aoff,
                                                u16* __restrict__ hbuf) {
  __shared__ u16 As[2][4096], Bs[2][4096];
  int work = xcd_swz(blockIdx.x, (H_ / 128) * (ROWSP / 128));
  int rt = work >> 4;                 // row-tile (A-panel shared by 16 n-tiles)
  int n0 = (work & 15) * 128;
  int row0 = rt * 128;
  if (row0 >= aoff[8]) return;
  int e = 0;
  while (row0 >= aoff[e + 1]) ++e;
  int t = threadIdx.x, wave = t >> 6, lane = t & 63;
  int wm = wave >> 1, wn = wave & 1;
  const u16* w1e = w1t + (size_t)e * H_ * D_;

  int ar = t >> 2, ac = stage_kc(t);
  int tok0 = tok_list[row0 + ar];       if ((unsigned)tok0 >= B_) tok0 = 0;
  int tok1 = tok_list[row0 + 64 + ar];  if ((unsigned)tok1 >= B_) tok1 = 0;
  const u16* a0 = xhi + (size_t)tok0 * D_ + ac;
  const u16* a1 = xhi + (size_t)tok1 * D_ + ac;
  const u16* bb0 = w1e + (size_t)(n0 + ar) * D_ + ac;
  const u16* bb1 = w1e + (size_t)(n0 + 64 + ar) * D_ + ac;

  const f32x4 z = {0.f, 0.f, 0.f, 0.f};
  f32x4 acc[4][4];
#pragma unroll
  for (int i = 0; i < 4; ++i)
#pragma unroll
    for (int j = 0; j < 4; ++j) acc[i][j] = z;

  // loop-invariant LDS pointers
  u16* dA = &As[0][t * 8];             // writes: dA(+2048) buf0, dA+4096(+2048) buf1
  u16* dB = &Bs[0][t * 8];
  const u16* rA = &As[0][wm * 2048 + frag_idx(lane, 0)];   // reads: +i*512, buf1 +4096
  const u16* rB = &Bs[0][wn * 2048 + frag_idx(lane, 0)];

  // prologue: stage tile 0 into buf0, advance globals to tile 1
  gload16(a0, dA);  gload16(a1, dA + 2048);
  gload16(bb0, dB); gload16(bb1, dB + 2048);
  a0 += 32; a1 += 32; bb0 += 32; bb1 += 32;
  __syncthreads();

  const int NT = D_ / 32;  // 32, even
  for (int kt = 0; kt < NT; kt += 2) {
    // step A: read buf0, stage tile kt+1 -> buf1
    gload16(a0, dA + 4096);  gload16(a1, dA + 6144);
    gload16(bb0, dB + 4096); gload16(bb1, dB + 6144);
    {
      s16x8 af[4], bf[4];
#pragma unroll
      for (int i = 0; i < 4; ++i) {
        af[i] = *(const s16x8*)(rA + i * 512);
        bf[i] = *(const s16x8*)(rB + i * 512);
      }
#pragma unroll
      for (int i = 0; i < 4; ++i)
#pragma unroll
        for (int j = 0; j < 4; ++j)
          acc[i][j] = __builtin_amdgcn_mfma_f32_16x16x32_bf16(af[i], bf[j], acc[i][j], 0, 0, 0);
    }
    __syncthreads();
    // step B: read buf1, stage tile kt+2 -> buf0 (if any)
    if (kt + 2 < NT) {
      gload16(a0 + 32, dA);  gload16(a1 + 32, dA + 2048);
      gload16(bb0 + 32, dB); gload16(bb1 + 32, dB + 2048);
    }
    {
      s16x8 af[4], bf[4];
#pragma unroll
      for (int i = 0; i < 4; ++i) {
        af[i] = *(const s16x8*)(rA + 4096 + i * 512);
        bf[i] = *(const s16x8*)(rB + 4096 + i * 512);
      }
#pragma unroll
      for (int i = 0; i < 4; ++i)
#pragma unroll
        for (int j = 0; j < 4; ++j)
          acc[i][j] = __builtin_amdgcn_mfma_f32_16x16x32_bf16(af[i], bf[j], acc[i][j], 0, 0, 0);
    }
    __syncthreads();
    a0 += 64; a1 += 64; bb0 += 64; bb1 += 64;
  }
#pragma unroll
  for (int j = 0; j < 4; ++j) {
    int col = n0 + wn * 64 + j * 16 + (lane & 15);
    float bias = b1v[e * H_ + col];
#pragma unroll
    for (int i = 0; i < 4; ++i)
#pragma unroll
      for (int q = 0; q < 4; ++q) {
        int row = row0 + wm * 64 + i * 16 + (lane >> 4) * 4 + q;
        float v = acc[i][j][q] + bias;
        hbuf[(size_t)row * H_ + col] = f2bf(v > 0.f ? v : 0.f);
      }
  }
}

// ---------- expert GEMM2: rbuf[row] = w * (h @ W2[e] + b2[e]) (bf16) ----------
__global__ __launch_bounds__(256) void k_egemm2(const u16* __restrict__ hbuf,
                                                const u16* __restrict__ w2t,
                                                const float* __restrict__ b2v,
                                                const int* __restrict__ aoff,
                                                const float* __restrict__ wroute,
                                                u16* __restrict__ rbuf) {
  __shared__ u16 As[2][4096], Bs[2][4096];
  int work = xcd_swz(blockIdx.x, (O_ / 128) * (ROWSP / 128));
  int rt = work >> 3;                 // row-tile (A-panel shared by 8 n-tiles)
  int n0 = (work & 7) * 128;
  int row0 = rt * 128;
  if (row0 >= aoff[8]) return;
  int e = 0;
  while (row0 >= aoff[e + 1]) ++e;
  int t = threadIdx.x, wave = t >> 6, lane = t & 63;
  int wm = wave >> 1, wn = wave & 1;
  const u16* w2e = w2t + (size_t)e * O_ * H_;

  int ar = t >> 2, ac = stage_kc(t);
  const u16* a0 = hbuf + (size_t)(row0 + ar) * H_ + ac;
  const u16* a1 = hbuf + (size_t)(row0 + 64 + ar) * H_ + ac;
  const u16* bb0 = w2e + (size_t)(n0 + ar) * H_ + ac;
  const u16* bb1 = w2e + (size_t)(n0 + 64 + ar) * H_ + ac;

  const f32x4 z = {0.f, 0.f, 0.f, 0.f};
  f32x4 acc[4][4];
#pragma unroll
  for (int i = 0; i < 4; ++i)
#pragma unroll
    for (int j = 0; j < 4; ++j) acc[i][j] = z;

  u16* dA = &As[0][t * 8];
  u16* dB = &Bs[0][t * 8];
  const u16* rA = &As[0][wm * 2048 + frag_idx(lane, 0)];
  const u16* rB = &Bs[0][wn * 2048 + frag_idx(lane, 0)];

  gload16(a0, dA);  gload16(a1, dA + 2048);
  gload16(bb0, dB); gload16(bb1, dB + 2048);
  a0 += 32; a1 += 32; bb0 += 32; bb1 += 32;
  __syncthreads();

  const int NT = H_ / 32;  // 64, even
  for (int kt = 0; kt < NT; kt += 2) {
    gload16(a0, dA + 4096);  gload16(a1, dA + 6144);
    gload16(bb0, dB + 4096); gload16(bb1, dB + 6144);
    {
      s16x8 af[4], bf[4];
#pragma unroll
      for (int i = 0; i < 4; ++i) {
        af[i] = *(const s16x8*)(rA + i * 512);
        bf[i] = *(const s16x8*)(rB + i * 512);
      }
#pragma unroll
      for (int i = 0; i < 4; ++i)
#pragma unroll
        for (int j = 0; j < 4; ++j)
          acc[i][j] = __builtin_amdgcn_mfma_f32_16x16x32_bf16(af[i], bf[j], acc[i][j], 0, 0, 0);
    }
    __syncthreads();
    if (kt + 2 < NT) {
      gload16(a0 + 32, dA);  gload16(a1 + 32, dA + 2048);
      gload16(bb0 + 32, dB); gload16(bb1 + 32, dB + 2048);
    }
    {
      s16x8 af[4], bf[4];
#pragma unroll
      for (int i = 0; i < 4; ++i) {
        af[i] = *(const s16x8*)(rA + 4096 + i * 512);
        bf[i] = *(const s16x8*)(rB + 4096 + i * 512);
      }
#pragma unroll
      for (int i = 0; i < 4; ++i)
#pragma unroll
        for (int j = 0; j < 4; ++j)
          acc[i][j] = __builtin_amdgcn_mfma_f32_16x16x32_bf16(af[i], bf[j], acc[i][j], 0, 0, 0);
    }
    __syncthreads();
    a0 += 64; a1 += 64; bb0 += 64; bb1 += 64;
  }
#pragma unroll
  for (int i = 0; i < 4; ++i)
#pragma unroll
    for (int q = 0; q < 4; ++q) {
      int row = row0 + wm * 64 + i * 16 + (lane >> 4) * 4 + q;
      float wv = wroute[row];
#pragma unroll
      for (int j = 0; j < 4; ++j) {
        int col = n0 + wn * 64 + j * 16 + (lane & 15);
        float bias = b2v[e * O_ + col];
        rbuf[(size_t)row * O_ + col] = f2bf((acc[i][j][q] + bias) * wv);
      }
    }
}

// ---------- combine: out[tok] = rbuf[pos0] + rbuf[pos1] ----------
__global__ __launch_bounds__(256) void k_combine(const u16* __restrict__ rbuf,
                                                 const int* __restrict__ pos_of,
                                                 float* __restrict__ out) {
  int t = threadIdx.x;
  int tok = blockIdx.x * 2 + (t >> 7);
  int c = (t & 127) * 8;
  int p0 = pos_of[tok * 2], p1 = pos_of[tok * 2 + 1];
  const u16* r0 = rbuf + (size_t)p0 * O_ + c;
  const u16* r1 = rbuf + (size_t)p1 * O_ + c;
  ushort4 a0 = *(const ushort4*)r0, a1 = *(const ushort4*)(r0 + 4);
  ushort4 b0 = *(const ushort4*)r1, b1 = *(const ushort4*)(r1 + 4);
  float4 o0, o1;
  o0.x = bf2f(a0.x) + bf2f(b0.x); o0.y = bf2f(a0.y) + bf2f(b0.y);
  o0.z = bf2f(a0.z) + bf2f(b0.z); o0.w = bf2f(a0.w) + bf2f(b0.w);
  o1.x = bf2f(a1.x) + bf2f(b1.x); o1.y = bf2f(a1.y) + bf2f(b1.y);
  o1.z = bf2f(a1.z) + bf2f(b1.z); o1.w = bf2f(a1.w) + bf2f(b1.w);
  float* op = out + (size_t)tok * O_ + c;
  *(float4*)op = o0; *(float4*)(op + 4) = o1;
}

// ---------- workspace layout (bytes) ----------
static const size_t o_xhi  = 0;                                    // 16MB
static const size_t o_xlo  = o_xhi + (size_t)B_ * D_ * 2;          // 16MB
static const size_t o_w1t  = o_xlo + (size_t)B_ * D_ * 2;          // 32MB
static const size_t o_w2t  = o_w1t + (size_t)E_ * H_ * D_ * 2;     // 32MB
static const size_t o_wg1h = o_w2t + (size_t)E_ * O_ * H_ * 2;     // 1MB
static const size_t o_wg1l = o_wg1h + (size_t)G_ * D_ * 2;         // 1MB
static const size_t o_G1   = o_wg1l + (size_t)G_ * D_ * 2;         // 16MB
static const size_t o_h    = o_G1 + (size_t)B_ * G_ * 4;           // 68MB
static const size_t o_idx  = o_h + (size_t)ROWSP * H_ * 2;
static const size_t o_wn   = o_idx + (size_t)B_ * 2 * 4;
static const size_t o_pos  = o_wn + (size_t)B_ * 2 * 4;
static const size_t o_tok  = o_pos + (size_t)B_ * 2 * 4;
static const size_t o_wr   = o_tok + (size_t)ROWSP * 4;
static const size_t o_cnt  = o_wr + (size_t)ROWSP * 4;   // zeroed by prep: counts(8), fill(8), ent, nflag
static const size_t o_fill = o_cnt + 32;
static const size_t o_ent  = o_cnt + 64;
static const size_t o_nfl  = o_cnt + 96;
static const size_t o_aoff = o_cnt + 128;
static const size_t o_logits = o_cnt + 256;
static const size_t o_flag   = o_logits + (size_t)B_ * 8 * 4;
// rbuf (bf16, 35.7MB) aliases xlo+w1t — both dead before k_egemm2 runs.
static const size_t o_rbuf = o_xlo;

extern "C" void kernel_launch(void* const* d_in, const int* in_sizes, int n_in,
                              void* d_out, int out_size, void* d_ws, size_t ws_size,
                              hipStream_t stream) {
  const float* x   = (const float*)d_in[0];
  const float* W1  = (const float*)d_in[1];
  const float* b1  = (const float*)d_in[2];
  const float* W2  = (const float*)d_in[3];
  const float* b2  = (const float*)d_in[4];
  const float* Wg1 = (const float*)d_in[5];
  const float* bg1 = (const float*)d_in[6];
  const float* Wg2 = (const float*)d_in[7];
  const float* bg2 = (const float*)d_in[8];
  float* out = (float*)d_out;
  char* ws = (char*)d_ws;

  u16* xhi  = (u16*)(ws + o_xhi);
  u16* xlo  = (u16*)(ws + o_xlo);
  u16* w1t  = (u16*)(ws + o_w1t);
  u16* w2t  = (u16*)(ws + o_w2t);
  u16* wg1h = (u16*)(ws + o_wg1h);
  u16* wg1l = (u16*)(ws + o_wg1l);
  float* G1 = (float*)(ws + o_G1);
  u16* hbuf = (u16*)(ws + o_h);
  int* topidx = (int*)(ws + o_idx);
  float* wnorm = (float*)(ws + o_wn);
  int* pos_of = (int*)(ws + o_pos);
  int* tok_list = (int*)(ws + o_tok);
  float* wroute = (float*)(ws + o_wr);
  int* counts = (int*)(ws + o_cnt);
  int* fill = (int*)(ws + o_fill);
  float* entacc = (float*)(ws + o_ent);
  int* nflag = (int*)(ws + o_nfl);
  int* aoff = (int*)(ws + o_aoff);
  float* logits = (float*)(ws + o_logits);
  int* flaglist = (int*)(ws + o_flag);
  u16* rbuf = (u16*)(ws + o_rbuf);

  k_prep<<<PREP_CAST_BLK + PREP_WG1_BLK + PREP_W1_BLK + PREP_W2_BLK, 256, 0, stream>>>(
      x, xhi, xlo, Wg1, wg1h, wg1l, W1, w1t, W2, w2t, counts);

  k_gate_gemm1<<<(G_ / 128) * (B_ / 64), 256, 0, stream>>>(xhi, xlo, wg1h, wg1l, bg1, G1);
  k_gate_logits<<<B_ / 4, 256, 0, stream>>>(G1, Wg2, bg2, logits, flaglist, nflag);
  k_gate_fixup<<<128, 256, 0, stream>>>(x, Wg1, bg1, Wg2, bg2, flaglist, nflag, logits);
  k_gate_final<<<B_ / 256, 256, 0, stream>>>(logits, topidx, wnorm, counts, entacc);
  k_scatter<<<(B_ * 2) / 256, 256, 0, stream>>>(topidx, wnorm, counts, entacc,
                                                fill, tok_list, wroute, pos_of, aoff,
                                                out + (size_t)B_ * O_);

  k_egemm1<<<(H_ / 128) * (ROWSP / 128), 256, 0, stream>>>(xhi, w1t, b1, tok_list, aoff, hbuf);
  k_egemm2<<<(O_ / 128) * (ROWSP / 128), 256, 0, stream>>>(hbuf, w2t, b2, aoff, wroute, rbuf);
  k_combine<<<B_ / 2, 256, 0, stream>>>(rbuf, pos_of, out);
}

// Round 16
// 488.914 us; speedup vs baseline: 1.1241x; 1.1241x over previous
//
#include <hip/hip_runtime.h>

#define B_ 8192
#define D_ 1024
#define O_ 1024
#define G_ 512
#define H_ 2048
#define E_ 8
#define ROWSP (B_ * 2 + E_ * 128)   // padded routed rows = 17408
#define TAU 0.01f

typedef unsigned short u16;
using f32x4  = __attribute__((ext_vector_type(4))) float;
using s16x8  = __attribute__((ext_vector_type(8))) short;

__device__ __forceinline__ u16 f2bf(float f) {
  union { float f; unsigned u; } v; v.f = f;
  unsigned r = v.u + 0x7FFFu + ((v.u >> 16) & 1u);
  return (u16)(r >> 16);
}
__device__ __forceinline__ float bf2f(u16 h) {
  union { unsigned u; float f; } v; v.u = ((unsigned)h) << 16; return v.f;
}
__device__ __forceinline__ void gload16(const void* g, void* l) {
  __builtin_amdgcn_global_load_lds(
      (const __attribute__((address_space(1))) unsigned int*)g,
      (__attribute__((address_space(3))) unsigned int*)l, 16, 0, 0);
}
// XCD-aware swizzle: hardware bid -> work id; XCD(bid)=bid%8 gets contiguous works.
__device__ __forceinline__ int xcd_swz(int bid, int nwg) {
  return (bid & 7) * (nwg >> 3) + (bid >> 3);
}
// Swizzled staging (proven R5): thread li stages logical chunk (li&3)^((li>>3)&3) of
// row li>>2 into physical slot li&3 (linear dest li*16B). Global 64B row contiguous.
__device__ __forceinline__ int stage_kc(int t) {
  return (((t & 3) ^ ((t >> 3) & 3)) * 8);
}
// 16x16x32 fragment read within a 64x32 swizzled subtile (2048 u16), proven R5
// (0 conflicts measured): row = i*16 + (lane&15), chunk = (lane>>4) ^ ((lane>>1)&3).
__device__ __forceinline__ int frag_idx(int lane, int i) {
  int row = i * 16 + (lane & 15);
  int s = (lane >> 4) ^ ((lane >> 1) & 3);
  return (row * 4 + s) * 8;
}

// ---------- merged preprocessing: cast x (hi/lo) + transpose-cast Wg1/W1/W2 + zero ctrs ----------
#define PREP_CAST_BLK (B_ * D_ / 4 / 256)          // 8192
#define PREP_WG1_BLK  ((G_ / 32) * (D_ / 32))      // 512
#define PREP_W1_BLK   ((H_ / 32) * (D_ / 32) * E_) // 16384
#define PREP_W2_BLK   ((O_ / 32) * (H_ / 32) * E_) // 16384

// Vectorized transpose-cast: float4 reads, ushort4 writes (both coalesced).
__device__ __forceinline__ void tr_cast_tile(const float* __restrict__ src,
                                             u16* __restrict__ dhi,
                                             u16* __restrict__ dlo,
                                             int R, int C, int bx, int by,
                                             float (*tile)[33], int t) {
  int c0 = bx * 32, r0 = by * 32;
  {
    int row = t >> 3, col4 = (t & 7) * 4;
    float4 v = *(const float4*)(src + (size_t)(r0 + row) * C + c0 + col4);
    tile[row][col4] = v.x; tile[row][col4 + 1] = v.y;
    tile[row][col4 + 2] = v.z; tile[row][col4 + 3] = v.w;
  }
  __syncthreads();
  {
    int c = t >> 3, r4 = (t & 7) * 4;
    float v0 = tile[r4 + 0][c], v1 = tile[r4 + 1][c];
    float v2 = tile[r4 + 2][c], v3 = tile[r4 + 3][c];
    ushort4 hi;
    hi.x = f2bf(v0); hi.y = f2bf(v1); hi.z = f2bf(v2); hi.w = f2bf(v3);
    *(ushort4*)(dhi + (size_t)(c0 + c) * R + r0 + r4) = hi;
    if (dlo) {
      ushort4 lo;
      lo.x = f2bf(v0 - bf2f(hi.x)); lo.y = f2bf(v1 - bf2f(hi.y));
      lo.z = f2bf(v2 - bf2f(hi.z)); lo.w = f2bf(v3 - bf2f(hi.w));
      *(ushort4*)(dlo + (size_t)(c0 + c) * R + r0 + r4) = lo;
    }
  }
}

__global__ __launch_bounds__(256) void k_prep(const float* __restrict__ x,
                                              u16* __restrict__ xhi, u16* __restrict__ xlo,
                                              const float* __restrict__ Wg1,
                                              u16* __restrict__ wg1h, u16* __restrict__ wg1l,
                                              const float* __restrict__ W1, u16* __restrict__ w1t,
                                              const float* __restrict__ W2, u16* __restrict__ w2t,
                                              int* __restrict__ zeroarea) {
  __shared__ float tile[32][33];
  int t = threadIdx.x;
  int b = blockIdx.x;
  if (b < PREP_CAST_BLK) {
    if (b == 0 && t < 32) zeroarea[t] = 0;   // counts/fill/ent/nflag
    int i = b * 256 + t;
    float4 v = ((const float4*)x)[i];
    u16 h0 = f2bf(v.x), h1 = f2bf(v.y), h2 = f2bf(v.z), h3 = f2bf(v.w);
    ushort4 hi; hi.x = h0; hi.y = h1; hi.z = h2; hi.w = h3;
    ushort4 lo;
    lo.x = f2bf(v.x - bf2f(h0)); lo.y = f2bf(v.y - bf2f(h1));
    lo.z = f2bf(v.z - bf2f(h2)); lo.w = f2bf(v.w - bf2f(h3));
    ((ushort4*)xhi)[i] = hi; ((ushort4*)xlo)[i] = lo;
    return;
  }
  b -= PREP_CAST_BLK;
  if (b < PREP_WG1_BLK) {
    tr_cast_tile(Wg1, wg1h, wg1l, D_, G_, b & 15, b >> 4, tile, t);
    return;
  }
  b -= PREP_WG1_BLK;
  if (b < PREP_W1_BLK) {
    int e = b >> 11, rr = b & 2047;
    size_t ofs = (size_t)e * D_ * H_;
    tr_cast_tile(W1 + ofs, w1t + ofs, nullptr, D_, H_, rr & 63, rr >> 6, tile, t);
    return;
  }
  b -= PREP_W1_BLK;
  {
    int e = b >> 11, rr = b & 2047;
    size_t ofs = (size_t)e * H_ * O_;
    tr_cast_tile(W2 + ofs, w2t + ofs, nullptr, H_, O_, rr & 31, rr >> 5, tile, t);
  }
}

// ---------- gate GEMM1: G1 = relu(x @ Wg1 + bg1), 3-pass split bf16, f32 out ----------
// 64x128 tiles (512 blocks). 4 waves 2M x 2N; wave = 32x64, acc[2][4].
__global__ __launch_bounds__(256) void k_gate_gemm1(const u16* __restrict__ xhi,
                                                    const u16* __restrict__ xlo,
                                                    const u16* __restrict__ whi,
                                                    const u16* __restrict__ wlo,
                                                    const float* __restrict__ bg1,
                                                    float* __restrict__ G1) {
  __shared__ u16 Ah[2048], Al[2048], Bh[4096], Bl[4096];
  int work = xcd_swz(blockIdx.x, (G_ / 128) * (B_ / 64));
  int m0 = (work >> 2) * 64, n0 = (work & 3) * 128;
  int t = threadIdx.x;
  int wave = t >> 6, lane = t & 63;
  int wm = wave >> 1, wn = wave & 1;

  const f32x4 z = {0.f, 0.f, 0.f, 0.f};
  f32x4 acc[2][4];
#pragma unroll
  for (int i = 0; i < 2; ++i)
#pragma unroll
    for (int j = 0; j < 4; ++j) acc[i][j] = z;

  int ar = t >> 2, ac = stage_kc(t);
  const u16* xh0 = xhi + (size_t)(m0 + ar) * D_ + ac;
  const u16* xl0 = xlo + (size_t)(m0 + ar) * D_ + ac;
  const u16* wh0 = whi + (size_t)(n0 + ar) * D_ + ac;
  const u16* wh1 = whi + (size_t)(n0 + 64 + ar) * D_ + ac;
  const u16* wl0 = wlo + (size_t)(n0 + ar) * D_ + ac;
  const u16* wl1 = wlo + (size_t)(n0 + 64 + ar) * D_ + ac;

  for (int k0 = 0; k0 < D_; k0 += 32) {
    gload16(xh0 + k0, &Ah[t * 8]);
    gload16(xl0 + k0, &Al[t * 8]);
    gload16(wh0 + k0, &Bh[t * 8]); gload16(wh1 + k0, &Bh[2048 + t * 8]);
    gload16(wl0 + k0, &Bl[t * 8]); gload16(wl1 + k0, &Bl[2048 + t * 8]);
    __syncthreads();
    s16x8 ah[2], al[2], bh[4], bl[4];
#pragma unroll
    for (int i = 0; i < 2; ++i) {
      ah[i] = *(const s16x8*)&Ah[frag_idx(lane, wm * 2 + i)];
      al[i] = *(const s16x8*)&Al[frag_idx(lane, wm * 2 + i)];
    }
#pragma unroll
    for (int j = 0; j < 4; ++j) {
      bh[j] = *(const s16x8*)&Bh[wn * 2048 + frag_idx(lane, j)];
      bl[j] = *(const s16x8*)&Bl[wn * 2048 + frag_idx(lane, j)];
    }
#pragma unroll
    for (int i = 0; i < 2; ++i)
#pragma unroll
      for (int j = 0; j < 4; ++j) {
        acc[i][j] = __builtin_amdgcn_mfma_f32_16x16x32_bf16(ah[i], bh[j], acc[i][j], 0, 0, 0);
        acc[i][j] = __builtin_amdgcn_mfma_f32_16x16x32_bf16(ah[i], bl[j], acc[i][j], 0, 0, 0);
        acc[i][j] = __builtin_amdgcn_mfma_f32_16x16x32_bf16(al[i], bh[j], acc[i][j], 0, 0, 0);
      }
    __syncthreads();
  }
#pragma unroll
  for (int j = 0; j < 4; ++j) {
    int col = n0 + wn * 64 + j * 16 + (lane & 15);
    float bias = bg1[col];
#pragma unroll
    for (int i = 0; i < 2; ++i)
#pragma unroll
      for (int q = 0; q < 4; ++q) {
        int row = m0 + wm * 32 + i * 16 + (lane >> 4) * 4 + q;
        float v = acc[i][j][q] + bias;
        G1[(size_t)row * G_ + col] = v > 0.f ? v : 0.f;
      }
  }
}

// ---------- gate logits: L = G1 @ Wg2 + bg2 (fp32, wave per row) + near-tie flagging ----------
__global__ __launch_bounds__(256) void k_gate_logits(const float* __restrict__ G1,
                                                     const float* __restrict__ Wg2,
                                                     const float* __restrict__ bg2,
                                                     float* __restrict__ logits,
                                                     int* __restrict__ flaglist,
                                                     int* __restrict__ nflag) {
  int t = threadIdx.x, wave = t >> 6, lane = t & 63;
  int row = blockIdx.x * 4 + wave;

  float4 g0 = *(const float4*)(G1 + (size_t)row * G_ + lane * 8);
  float4 g1 = *(const float4*)(G1 + (size_t)row * G_ + lane * 8 + 4);
  float g[8] = {g0.x, g0.y, g0.z, g0.w, g1.x, g1.y, g1.z, g1.w};
  float p[8] = {0, 0, 0, 0, 0, 0, 0, 0};
#pragma unroll
  for (int cc = 0; cc < 8; ++cc) {
    int c = lane * 8 + cc;
    float4 w0 = *(const float4*)(Wg2 + c * 8);
    float4 w1 = *(const float4*)(Wg2 + c * 8 + 4);
    p[0] += g[cc] * w0.x; p[1] += g[cc] * w0.y; p[2] += g[cc] * w0.z; p[3] += g[cc] * w0.w;
    p[4] += g[cc] * w1.x; p[5] += g[cc] * w1.y; p[6] += g[cc] * w1.z; p[7] += g[cc] * w1.w;
  }
#pragma unroll
  for (int off = 32; off >= 1; off >>= 1)
#pragma unroll
    for (int e = 0; e < 8; ++e) p[e] += __shfl_xor(p[e], off);
  if (lane == 0) {
    float l1 = -1e30f, l2 = -1e30f, l3 = -1e30f;
#pragma unroll
    for (int e = 0; e < 8; ++e) {
      float v = p[e] + bg2[e];
      logits[(size_t)row * 8 + e] = v;
      if (v > l1) { l3 = l2; l2 = l1; l1 = v; }
      else if (v > l2) { l3 = l2; l2 = v; }
      else if (v > l3) { l3 = v; }
    }
    if (l2 - l3 < TAU) {
      int pos = atomicAdd(nflag, 1);
      flaglist[pos] = row;
    }
  }
}

// ---------- exact fp32 recompute for flagged rows ----------
__global__ __launch_bounds__(256) void k_gate_fixup(const float* __restrict__ x,
                                                    const float* __restrict__ Wg1,
                                                    const float* __restrict__ bg1,
                                                    const float* __restrict__ Wg2,
                                                    const float* __restrict__ bg2,
                                                    const int* __restrict__ flaglist,
                                                    const int* __restrict__ nflag,
                                                    float* __restrict__ logits) {
  __shared__ float xs[1024];
  __shared__ float red[256][9];
  int t = threadIdx.x;
  int n = *nflag;
  for (int i = blockIdx.x; i < n; i += gridDim.x) {
    int row = flaglist[i];
    ((float4*)xs)[t] = ((const float4*)(x + (size_t)row * D_))[t];
    __syncthreads();
    int c0 = t * 2;
    float h0 = 0.f, h1 = 0.f;
#pragma unroll 8
    for (int d = 0; d < D_; ++d) {
      float xv = xs[d];
      float2 w = *(const float2*)(Wg1 + (size_t)d * G_ + c0);
      h0 += xv * w.x; h1 += xv * w.y;
    }
    h0 += bg1[c0]; h1 += bg1[c0 + 1];
    h0 = h0 > 0.f ? h0 : 0.f; h1 = h1 > 0.f ? h1 : 0.f;
#pragma unroll
    for (int e = 0; e < 8; ++e)
      red[t][e] = h0 * Wg2[c0 * 8 + e] + h1 * Wg2[(c0 + 1) * 8 + e];
    __syncthreads();
    for (int s = 128; s >= 1; s >>= 1) {
      if (t < s) {
#pragma unroll
        for (int e = 0; e < 8; ++e) red[t][e] += red[t + s][e];
      }
      __syncthreads();
    }
    if (t < 8) logits[(size_t)row * 8 + t] = red[0][t] + bg2[t];
    __syncthreads();
  }
}

// ---------- final gate ----------
__global__ __launch_bounds__(256) void k_gate_final(const float* __restrict__ logits,
                                                    int* __restrict__ topidx,
                                                    float* __restrict__ wnorm,
                                                    int* __restrict__ counts,
                                                    float* __restrict__ entacc) {
  __shared__ int cnt_s[8];
  __shared__ float ent_s[4];
  int t = threadIdx.x;
  if (t < 8) cnt_s[t] = 0;
  __syncthreads();
  int row = blockIdx.x * 256 + t;
  float4 a = ((const float4*)logits)[(size_t)row * 2];
  float4 b = ((const float4*)logits)[(size_t)row * 2 + 1];
  float L[8] = {a.x, a.y, a.z, a.w, b.x, b.y, b.z, b.w};
  float m = L[0];
#pragma unroll
  for (int e = 1; e < 8; ++e) m = fmaxf(m, L[e]);
  float s[8], Z = 0.f;
#pragma unroll
  for (int e = 0; e < 8; ++e) { s[e] = expf(L[e] - m); Z += s[e]; }
  float inv = 1.f / Z;
  float sc[8];
#pragma unroll
  for (int e = 0; e < 8; ++e) sc[e] = s[e] * inv;
  int i1 = 0;
#pragma unroll
  for (int e = 1; e < 8; ++e) if (L[e] > L[i1]) i1 = e;
  int i2 = (i1 == 0) ? 1 : 0;
#pragma unroll
  for (int e = 0; e < 8; ++e) if (e != i1 && L[e] > L[i2]) i2 = e;
  float s1 = sc[i1], s2 = sc[i2];
  float denom = s1 + s2 + 1e-9f;
  topidx[row * 2] = i1; topidx[row * 2 + 1] = i2;
  wnorm[row * 2] = s1 / denom; wnorm[row * 2 + 1] = s2 / denom;
  atomicAdd(&cnt_s[i1], 1); atomicAdd(&cnt_s[i2], 1);
  float ent = 0.f;
#pragma unroll
  for (int e = 0; e < 8; ++e) ent -= sc[e] * logf(sc[e] + 1e-9f);
#pragma unroll
  for (int off = 32; off >= 1; off >>= 1) ent += __shfl_xor(ent, off);
  if ((t & 63) == 0) ent_s[t >> 6] = ent;
  __syncthreads();
  if (t == 0) atomicAdd(entacc, ent_s[0] + ent_s[1] + ent_s[2] + ent_s[3]);
  if (t < 8) atomicAdd(&counts[t], cnt_s[t]);
}

// ---------- scatter routing (+ inline scan: every block derives aoff; block 0 writes aux) ----------
__global__ __launch_bounds__(256) void k_scatter(const int* __restrict__ topidx,
                                                 const float* __restrict__ wnorm,
                                                 const int* __restrict__ counts,
                                                 const float* __restrict__ entacc,
                                                 int* __restrict__ fill,
                                                 int* __restrict__ tok_list,
                                                 float* __restrict__ wroute,
                                                 int* __restrict__ pos_of,
                                                 int* __restrict__ aoff,
                                                 float* __restrict__ aux_out) {
  __shared__ int aoff_s[9];
  int t = threadIdx.x;
  if (t == 0) {
    int off = 0; aoff_s[0] = 0;
    for (int e = 0; e < 8; ++e) {
      off += ((counts[e] + 127) >> 7) << 7;
      aoff_s[e + 1] = off;
    }
    if (blockIdx.x == 0) {
      for (int e = 0; e < 9; ++e) aoff[e] = aoff_s[e];
      float mean = 0.f, ld[8];
      for (int e = 0; e < 8; ++e) { ld[e] = (float)counts[e] / (8192.0f + 1e-9f); mean += ld[e]; }
      mean *= 0.125f;
      float var = 0.f;
      for (int e = 0; e < 8; ++e) { float d = ld[e] - mean; var += d * d; }
      var *= (1.0f / 7.0f);
      *aux_out = var + entacc[0] / 8192.0f;
    }
  }
  __syncthreads();
  int i = blockIdx.x * 256 + t;
  int e = topidx[i];
  int pos = aoff_s[e] + atomicAdd(&fill[e], 1);
  tok_list[pos] = i >> 1;
  wroute[pos] = wnorm[i];
  pos_of[i] = pos;
}

// ==================== R5-proven 128x128 expert GEMMs (16x16x32, 0 conflicts) ====================
// 4 waves (2M x 2N), per-wave 64x64 (acc[4][4]). BK=32, dbuf, one barrier per K-step.

// ---------- expert GEMM1: h = relu(gather(x) @ W1[e] + b1[e]) -> bf16 ----------
__global__ __launch_bounds__(256) void k_egemm1(const u16* __restrict__ xhi,
                                                const u16* __restrict__ w1t,
                                                const float* __restrict__ b1v,
                                                const int* __restrict__ tok_list,
                                                const int* __restrict__ aoff,
                                                u16* __restrict__ hbuf) {
  __shared__ u16 As[2][4096], Bs[2][4096];
  int work = xcd_swz(blockIdx.x, (H_ / 128) * (ROWSP / 128));
  int rt = work >> 4;                 // row-tile (A-panel shared by 16 n-tiles)
  int n0 = (work & 15) * 128;
  int row0 = rt * 128;
  if (row0 >= aoff[8]) return;
  int e = 0;
  while (row0 >= aoff[e + 1]) ++e;
  int t = threadIdx.x, wave = t >> 6, lane = t & 63;
  int wm = wave >> 1, wn = wave & 1;
  const u16* w1e = w1t + (size_t)e * H_ * D_;

  int ar = t >> 2, ac = stage_kc(t);
  int tok0 = tok_list[row0 + ar];       if ((unsigned)tok0 >= B_) tok0 = 0;
  int tok1 = tok_list[row0 + 64 + ar];  if ((unsigned)tok1 >= B_) tok1 = 0;
  const u16* a0 = xhi + (size_t)tok0 * D_ + ac;
  const u16* a1 = xhi + (size_t)tok1 * D_ + ac;
  const u16* bb0 = w1e + (size_t)(n0 + ar) * D_ + ac;
  const u16* bb1 = w1e + (size_t)(n0 + 64 + ar) * D_ + ac;

  const f32x4 z = {0.f, 0.f, 0.f, 0.f};
  f32x4 acc[4][4];
#pragma unroll
  for (int i = 0; i < 4; ++i)
#pragma unroll
    for (int j = 0; j < 4; ++j) acc[i][j] = z;

  // prologue: stage K-tile 0 into buf 0
  gload16(a0, &As[0][t * 8]);  gload16(a1, &As[0][2048 + t * 8]);
  gload16(bb0, &Bs[0][t * 8]); gload16(bb1, &Bs[0][2048 + t * 8]);
  __syncthreads();

  const int NT = D_ / 32;
  for (int kt = 0; kt < NT; ++kt) {
    int cur = kt & 1, nxt = cur ^ 1;
    if (kt + 1 < NT) {
      int kk = (kt + 1) * 32;
      gload16(a0 + kk, &As[nxt][t * 8]);  gload16(a1 + kk, &As[nxt][2048 + t * 8]);
      gload16(bb0 + kk, &Bs[nxt][t * 8]); gload16(bb1 + kk, &Bs[nxt][2048 + t * 8]);
    }
    s16x8 af[4], bf[4];
#pragma unroll
    for (int i = 0; i < 4; ++i) {
      af[i] = *(const s16x8*)&As[cur][wm * 2048 + frag_idx(lane, i)];
      bf[i] = *(const s16x8*)&Bs[cur][wn * 2048 + frag_idx(lane, i)];
    }
#pragma unroll
    for (int i = 0; i < 4; ++i)
#pragma unroll
      for (int j = 0; j < 4; ++j)
        acc[i][j] = __builtin_amdgcn_mfma_f32_16x16x32_bf16(af[i], bf[j], acc[i][j], 0, 0, 0);
    __syncthreads();
  }
#pragma unroll
  for (int j = 0; j < 4; ++j) {
    int col = n0 + wn * 64 + j * 16 + (lane & 15);
    float bias = b1v[e * H_ + col];
#pragma unroll
    for (int i = 0; i < 4; ++i)
#pragma unroll
      for (int q = 0; q < 4; ++q) {
        int row = row0 + wm * 64 + i * 16 + (lane >> 4) * 4 + q;
        float v = acc[i][j][q] + bias;
        hbuf[(size_t)row * H_ + col] = f2bf(v > 0.f ? v : 0.f);
      }
  }
}

// ---------- expert GEMM2: rbuf[row] = w * (h @ W2[e] + b2[e]) (bf16) ----------
__global__ __launch_bounds__(256) void k_egemm2(const u16* __restrict__ hbuf,
                                                const u16* __restrict__ w2t,
                                                const float* __restrict__ b2v,
                                                const int* __restrict__ aoff,
                                                const float* __restrict__ wroute,
                                                u16* __restrict__ rbuf) {
  __shared__ u16 As[2][4096], Bs[2][4096];
  int work = xcd_swz(blockIdx.x, (O_ / 128) * (ROWSP / 128));
  int rt = work >> 3;                 // row-tile (A-panel shared by 8 n-tiles)
  int n0 = (work & 7) * 128;
  int row0 = rt * 128;
  if (row0 >= aoff[8]) return;
  int e = 0;
  while (row0 >= aoff[e + 1]) ++e;
  int t = threadIdx.x, wave = t >> 6, lane = t & 63;
  int wm = wave >> 1, wn = wave & 1;
  const u16* w2e = w2t + (size_t)e * O_ * H_;

  int ar = t >> 2, ac = stage_kc(t);
  const u16* a0 = hbuf + (size_t)(row0 + ar) * H_ + ac;
  const u16* a1 = hbuf + (size_t)(row0 + 64 + ar) * H_ + ac;
  const u16* bb0 = w2e + (size_t)(n0 + ar) * H_ + ac;
  const u16* bb1 = w2e + (size_t)(n0 + 64 + ar) * H_ + ac;

  const f32x4 z = {0.f, 0.f, 0.f, 0.f};
  f32x4 acc[4][4];
#pragma unroll
  for (int i = 0; i < 4; ++i)
#pragma unroll
    for (int j = 0; j < 4; ++j) acc[i][j] = z;

  gload16(a0, &As[0][t * 8]);  gload16(a1, &As[0][2048 + t * 8]);
  gload16(bb0, &Bs[0][t * 8]); gload16(bb1, &Bs[0][2048 + t * 8]);
  __syncthreads();

  const int NT = H_ / 32;
  for (int kt = 0; kt < NT; ++kt) {
    int cur = kt & 1, nxt = cur ^ 1;
    if (kt + 1 < NT) {
      int kk = (kt + 1) * 32;
      gload16(a0 + kk, &As[nxt][t * 8]);  gload16(a1 + kk, &As[nxt][2048 + t * 8]);
      gload16(bb0 + kk, &Bs[nxt][t * 8]); gload16(bb1 + kk, &Bs[nxt][2048 + t * 8]);
    }
    s16x8 af[4], bf[4];
#pragma unroll
    for (int i = 0; i < 4; ++i) {
      af[i] = *(const s16x8*)&As[cur][wm * 2048 + frag_idx(lane, i)];
      bf[i] = *(const s16x8*)&Bs[cur][wn * 2048 + frag_idx(lane, i)];
    }
#pragma unroll
    for (int i = 0; i < 4; ++i)
#pragma unroll
      for (int j = 0; j < 4; ++j)
        acc[i][j] = __builtin_amdgcn_mfma_f32_16x16x32_bf16(af[i], bf[j], acc[i][j], 0, 0, 0);
    __syncthreads();
  }
#pragma unroll
  for (int i = 0; i < 4; ++i)
#pragma unroll
    for (int q = 0; q < 4; ++q) {
      int row = row0 + wm * 64 + i * 16 + (lane >> 4) * 4 + q;
      float wv = wroute[row];
#pragma unroll
      for (int j = 0; j < 4; ++j) {
        int col = n0 + wn * 64 + j * 16 + (lane & 15);
        float bias = b2v[e * O_ + col];
        rbuf[(size_t)row * O_ + col] = f2bf((acc[i][j][q] + bias) * wv);
      }
    }
}

// ---------- combine: out[tok] = rbuf[pos0] + rbuf[pos1] ----------
__global__ __launch_bounds__(256) void k_combine(const u16* __restrict__ rbuf,
                                                 const int* __restrict__ pos_of,
                                                 float* __restrict__ out) {
  int t = threadIdx.x;
  int tok = blockIdx.x * 2 + (t >> 7);
  int c = (t & 127) * 8;
  int p0 = pos_of[tok * 2], p1 = pos_of[tok * 2 + 1];
  const u16* r0 = rbuf + (size_t)p0 * O_ + c;
  const u16* r1 = rbuf + (size_t)p1 * O_ + c;
  ushort4 a0 = *(const ushort4*)r0, a1 = *(const ushort4*)(r0 + 4);
  ushort4 b0 = *(const ushort4*)r1, b1 = *(const ushort4*)(r1 + 4);
  float4 o0, o1;
  o0.x = bf2f(a0.x) + bf2f(b0.x); o0.y = bf2f(a0.y) + bf2f(b0.y);
  o0.z = bf2f(a0.z) + bf2f(b0.z); o0.w = bf2f(a0.w) + bf2f(b0.w);
  o1.x = bf2f(a1.x) + bf2f(b1.x); o1.y = bf2f(a1.y) + bf2f(b1.y);
  o1.z = bf2f(a1.z) + bf2f(b1.z); o1.w = bf2f(a1.w) + bf2f(b1.w);
  float* op = out + (size_t)tok * O_ + c;
  *(float4*)op = o0; *(float4*)(op + 4) = o1;
}

// ---------- workspace layout (bytes) ----------
static const size_t o_xhi  = 0;                                    // 16MB
static const size_t o_xlo  = o_xhi + (size_t)B_ * D_ * 2;          // 16MB
static const size_t o_w1t  = o_xlo + (size_t)B_ * D_ * 2;          // 32MB
static const size_t o_w2t  = o_w1t + (size_t)E_ * H_ * D_ * 2;     // 32MB
static const size_t o_wg1h = o_w2t + (size_t)E_ * O_ * H_ * 2;     // 1MB
static const size_t o_wg1l = o_wg1h + (size_t)G_ * D_ * 2;         // 1MB
static const size_t o_G1   = o_wg1l + (size_t)G_ * D_ * 2;         // 16MB
static const size_t o_h    = o_G1 + (size_t)B_ * G_ * 4;           // 68MB
static const size_t o_idx  = o_h + (size_t)ROWSP * H_ * 2;
static const size_t o_wn   = o_idx + (size_t)B_ * 2 * 4;
static const size_t o_pos  = o_wn + (size_t)B_ * 2 * 4;
static const size_t o_tok  = o_pos + (size_t)B_ * 2 * 4;
static const size_t o_wr   = o_tok + (size_t)ROWSP * 4;
static const size_t o_cnt  = o_wr + (size_t)ROWSP * 4;   // zeroed by prep: counts(8), fill(8), ent, nflag
static const size_t o_fill = o_cnt + 32;
static const size_t o_ent  = o_cnt + 64;
static const size_t o_nfl  = o_cnt + 96;
static const size_t o_aoff = o_cnt + 128;
static const size_t o_logits = o_cnt + 256;
static const size_t o_flag   = o_logits + (size_t)B_ * 8 * 4;
// rbuf (bf16, 35.7MB) aliases xlo+w1t — both dead before k_egemm2 runs.
static const size_t o_rbuf = o_xlo;

extern "C" void kernel_launch(void* const* d_in, const int* in_sizes, int n_in,
                              void* d_out, int out_size, void* d_ws, size_t ws_size,
                              hipStream_t stream) {
  const float* x   = (const float*)d_in[0];
  const float* W1  = (const float*)d_in[1];
  const float* b1  = (const float*)d_in[2];
  const float* W2  = (const float*)d_in[3];
  const float* b2  = (const float*)d_in[4];
  const float* Wg1 = (const float*)d_in[5];
  const float* bg1 = (const float*)d_in[6];
  const float* Wg2 = (const float*)d_in[7];
  const float* bg2 = (const float*)d_in[8];
  float* out = (float*)d_out;
  char* ws = (char*)d_ws;

  u16* xhi  = (u16*)(ws + o_xhi);
  u16* xlo  = (u16*)(ws + o_xlo);
  u16* w1t  = (u16*)(ws + o_w1t);
  u16* w2t  = (u16*)(ws + o_w2t);
  u16* wg1h = (u16*)(ws + o_wg1h);
  u16* wg1l = (u16*)(ws + o_wg1l);
  float* G1 = (float*)(ws + o_G1);
  u16* hbuf = (u16*)(ws + o_h);
  int* topidx = (int*)(ws + o_idx);
  float* wnorm = (float*)(ws + o_wn);
  int* pos_of = (int*)(ws + o_pos);
  int* tok_list = (int*)(ws + o_tok);
  float* wroute = (float*)(ws + o_wr);
  int* counts = (int*)(ws + o_cnt);
  int* fill = (int*)(ws + o_fill);
  float* entacc = (float*)(ws + o_ent);
  int* nflag = (int*)(ws + o_nfl);
  int* aoff = (int*)(ws + o_aoff);
  float* logits = (float*)(ws + o_logits);
  int* flaglist = (int*)(ws + o_flag);
  u16* rbuf = (u16*)(ws + o_rbuf);

  k_prep<<<PREP_CAST_BLK + PREP_WG1_BLK + PREP_W1_BLK + PREP_W2_BLK, 256, 0, stream>>>(
      x, xhi, xlo, Wg1, wg1h, wg1l, W1, w1t, W2, w2t, counts);

  k_gate_gemm1<<<(G_ / 128) * (B_ / 64), 256, 0, stream>>>(xhi, xlo, wg1h, wg1l, bg1, G1);
  k_gate_logits<<<B_ / 4, 256, 0, stream>>>(G1, Wg2, bg2, logits, flaglist, nflag);
  k_gate_fixup<<<128, 256, 0, stream>>>(x, Wg1, bg1, Wg2, bg2, flaglist, nflag, logits);
  k_gate_final<<<B_ / 256, 256, 0, stream>>>(logits, topidx, wnorm, counts, entacc);
  k_scatter<<<(B_ * 2) / 256, 256, 0, stream>>>(topidx, wnorm, counts, entacc,
                                                fill, tok_list, wroute, pos_of, aoff,
                                                out + (size_t)B_ * O_);

  k_egemm1<<<(H_ / 128) * (ROWSP / 128), 256, 0, stream>>>(xhi, w1t, b1, tok_list, aoff, hbuf);
  k_egemm2<<<(O_ / 128) * (ROWSP / 128), 256, 0, stream>>>(hbuf, w2t, b2, aoff, wroute, rbuf);
  k_combine<<<B_ / 2, 256, 0, stream>>>(rbuf, pos_of, out);
}